// Round 7
// baseline (882.724 us; speedup 1.0000x reference)
//
#include <hip/hip_runtime.h>

#define HIDDEN 128
#define TSTEPS 512
#define NFUT 50
#define BR 8           // batch rows per block -> grid 512 = 2 blocks/CU
#define THREADS 256    // 4 waves/block; 2 blocks/CU -> only 2 waves/SIMD needed
#define HPITCH 136     // h row pitch in bf16 (272B rows: 16B-aligned for b128)

typedef __bf16 bf16x8 __attribute__((ext_vector_type(8)));
typedef float floatx4 __attribute__((ext_vector_type(4)));
typedef float f32x2 __attribute__((ext_vector_type(2)));

union B8 { int4 i; bf16x8 v; };

#if defined(__has_builtin)
#  if __has_builtin(__builtin_amdgcn_exp2f)
#    define EXP2F(x) __builtin_amdgcn_exp2f(x)
#  else
#    define EXP2F(x) exp2f(x)
#  endif
#  if __has_builtin(__builtin_amdgcn_rcpf)
#    define RCPF(x) __builtin_amdgcn_rcpf(x)
#  else
#    define RCPF(x) (1.0f / (x))
#  endif
#  if __has_builtin(__builtin_amdgcn_s_setprio)
#    define SETPRIO(p) __builtin_amdgcn_s_setprio(p)
#  else
#    define SETPRIO(p)
#  endif
#  if __has_builtin(__builtin_amdgcn_s_sleep)
#    define SSLEEP(n) __builtin_amdgcn_s_sleep(n)
#  else
#    define SSLEEP(n)
#  endif
#else
#  define EXP2F(x) exp2f(x)
#  define RCPF(x) (1.0f / (x))
#  define SETPRIO(p)
#  define SSLEEP(n)
#endif

#define L2E  1.4426950408889634f
#define L2E2 2.8853900817779268f

// R4/R6 lesson: two 8-wave blocks need 4 waves/SIMD -> co-residency dies for
// VGPR>64 (R6: occupancy 23.6% = 1 block, dur = 2 serialized rounds). 4-wave
// blocks need only 2 waves/SIMD: any VGPR<=256 co-resides. (256,2) -> cap 256.
__global__ __launch_bounds__(THREADS, 2)
void lstm_forecast_kernel(const float* __restrict__ x,
                          const float* __restrict__ W_ih,
                          const float* __restrict__ W_hh,
                          const float* __restrict__ b_ih,
                          const float* __restrict__ b_hh,
                          const float* __restrict__ fc_w,
                          const float* __restrict__ fc_b,
                          float* __restrict__ out) {
    // LDS: xa 32KB + h 8.7KB + fcw 1KB ~= 42KB -> 2 blocks/CU (85KB of 160KB)
    __shared__ __align__(16) uint2  xa[TSTEPS * BR];        // (x0h,x1h),(x0r,x1r) bf16 splits
    __shared__ __align__(16) __bf16 h_lds[2][16 * HPITCH];  // 16 rows for MFMA B; rows 8-15 stay 0
    __shared__ __align__(16) float  fcw_lds[2][HIDDEN];

    const int tid  = threadIdx.x;
    const int wave = tid >> 6;          // 0..3
    const int lane = tid & 63;
    const int quad = lane >> 4;
    const int l15  = lane & 15;
    const int hi8  = (lane >> 3) & 1;   // l15 >= 8: this lane ews cols +2,3 of row l15-8
    const int row8 = lane & 7;          // real batch row this lane ews / reads x for
    const int rb   = blockIdx.x * BR;

    fcw_lds[tid >> 7][tid & 127] = fc_w[tid];   // 256 threads cover 256 exactly

    // ---- stage x as bf16 hi/lo splits: xa[t][row] (feeds the x-MFMA) ----
    {
        const int row = tid & 7;
        for (int tb = tid >> 3; tb < TSTEPS; tb += THREADS >> 3) {
            float2 xv = *(const float2*)&x[(size_t)(rb + row) * (2 * TSTEPS) + tb * 2];
            __bf16 x0h = (__bf16)xv.x, x1h = (__bf16)xv.y;
            __bf16 x0r = (__bf16)(xv.x - (float)x0h);
            __bf16 x1r = (__bf16)(xv.y - (float)x1h);
            uint2 d;
            d.x = (unsigned)__builtin_bit_cast(unsigned short, x0h) |
                  ((unsigned)__builtin_bit_cast(unsigned short, x1h) << 16);
            d.y = (unsigned)__builtin_bit_cast(unsigned short, x0r) |
                  ((unsigned)__builtin_bit_cast(unsigned short, x1r) << 16);
            xa[tb * BR + row] = d;
        }
    }
    // zero both h buffers fully: rows 8-15 are never written and must stay 0
    for (int i = tid; i < 2 * 16 * HPITCH; i += THREADS) (&h_lds[0][0])[i] = (__bf16)0.0f;

    // ---- weights -> registers, pre-scaled so MFMA outputs are exp2-ready ----
    // gate scale: i,f,o -> -log2(e); g -> -2*log2(e)
    // Transposed MFMA: bfrag/bfx = A operand (m = gate col), h/x = B operand
    // (n = batch row = l15; rows 8-15 zero). Each wave owns 32 cols = 2 sets of 16.
    // C layout: n(=l15) = batch row, m(=quad*4+reg) = col offset within the set.
    bf16x8 bfrag[2][4][4];  // [set][gate][kchunk] scaled W_hh (later W_eff): 128 VGPRs
    B8 bfx[2][4];           // scaled W_ih + bias hi/lo, quad0 k-slots only
    float gs[4];
    const float fcb0 = fc_b[0], fcb1 = fc_b[1];
#pragma unroll
    for (int g = 0; g < 4; ++g) gs[g] = (g == 2) ? -L2E2 : -L2E;
#pragma unroll
    for (int s = 0; s < 2; ++s) {
        const int ub = wave * 32 + s * 16 + l15;   // A-layout gate col
#pragma unroll
        for (int g = 0; g < 4; ++g) {
            const int cg = g * HIDDEN + ub;
            const float w0 = W_ih[cg * 2 + 0];
            const float w1 = W_ih[cg * 2 + 1];
            const float bs = b_ih[cg] + b_hh[cg];
#pragma unroll
            for (int ks = 0; ks < 4; ++ks) {
                const float* wp = W_hh + (size_t)cg * HIDDEN + ks * 32 + quad * 8;
                bf16x8 bb;
#pragma unroll
                for (int j = 0; j < 8; ++j) bb[j] = (__bf16)(gs[g] * wp[j]);
                bfrag[s][g][ks] = bb;
            }
            B8 t; t.i = make_int4(0, 0, 0, 0);
            if (quad == 0) {
                const float w0s = gs[g] * w0, w1s = gs[g] * w1, bss = gs[g] * bs;
                __bf16 w0h = (__bf16)w0s, w1h = (__bf16)w1s;
                __bf16 w0l = (__bf16)(w0s - (float)w0h);
                __bf16 w1l = (__bf16)(w1s - (float)w1h);
                __bf16 bh  = (__bf16)bss;
                __bf16 bl  = (__bf16)(bss - (float)bh);
                bf16x8 bv = {w0h, w1h, bh, bl, w0h, w1h, w0l, w1l};
                t.v = bv;
            }
            bfx[s][g] = t;
        }
    }

    const unsigned ones2 = 0x3F803F80u;  // bf16(1.0) x2
    const int hrow = l15 * HPITCH;       // B-operand read row (0..15; 8-15 are zeros)
    f32x2 cst[2] = {{0.f, 0.f}, {0.f, 0.f}};  // one cell-pair per set

    auto mk = [](float a, float b) { f32x2 r; r.x = a; r.y = b; return r; };
    auto pk2 = [](f32x2 hn) -> unsigned {
        return (unsigned)__builtin_bit_cast(unsigned short, (__bf16)hn.x)
             | ((unsigned)__builtin_bit_cast(unsigned short, (__bf16)hn.y) << 16);
    };

    // ew for one cell-pair: 10 exp + 2 batched rcp
    auto ewPair = [&](f32x2 gi, f32x2 gf, f32x2 gg, f32x2 go, f32x2& c) -> unsigned {
        f32x2 ea, ec, eb, eo;
        ea.x = EXP2F(gi.x); ea.y = EXP2F(gi.y);   // e^-i
        ec.x = EXP2F(gf.x); ec.y = EXP2F(gf.y);   // e^-f
        eb.x = EXP2F(gg.x); eb.y = EXP2F(gg.y);   // e^-2g
        eo.x = EXP2F(go.x); eo.y = EXP2F(go.y);   // e^-o
        const f32x2 A1 = 1.f + ea, B1 = 1.f + eb, C1 = 1.f + ec;
        const f32x2 P  = A1 * B1;
        const f32x2 PC = P * C1;
        f32x2 R;                                  // batched: 1 rcp for the pair
        { const float I = RCPF(PC.x * PC.y); R.x = I * PC.y; R.y = I * PC.x; }
        const f32x2 sfv = P * R;                  // sigmoid(f)
        const f32x2 igv = (1.f - eb) * (C1 * R);  // sigmoid(i)*tanh(g)
        const f32x2 cn  = sfv * c + igv;
        c = cn;
        const f32x2 am = -L2E2 * cn;
        f32x2 ed;
        ed.x = EXP2F(fminf(am.x, 29.f));          // c clamped at -10 (tanh err < 4e-9)
        ed.y = EXP2F(fminf(am.y, 29.f));
        const f32x2 E = (1.f + ed) * (1.f + eo);
        f32x2 R2;                                 // batched: 1 rcp for the pair
        { const float J = RCPF(E.x * E.y); R2.x = J * E.y; R2.y = J * E.x; }
        const f32x2 hn = (1.f - ed) * R2;         // sigmoid(o)*tanh(c)
        return pk2(hn);
    };

    // post-MFMA per set: hi half-lanes take acc[2],[3] from lane^8 (one ds_swizzle
    // each), ew one pair, one b32 write. Shuffle AFTER accumulation -> exact f32.
    auto finish = [&](floatx4 (&acc)[2][4], __bf16* hd) {
#pragma unroll
        for (int s = 0; s < 2; ++s) {
            const float s20 = __shfl_xor(acc[s][0][2], 8), s30 = __shfl_xor(acc[s][0][3], 8);
            const float s21 = __shfl_xor(acc[s][1][2], 8), s31 = __shfl_xor(acc[s][1][3], 8);
            const float s22 = __shfl_xor(acc[s][2][2], 8), s32 = __shfl_xor(acc[s][2][3], 8);
            const float s23 = __shfl_xor(acc[s][3][2], 8), s33 = __shfl_xor(acc[s][3][3], 8);
            const f32x2 gi = hi8 ? mk(s20, s30) : mk(acc[s][0][0], acc[s][0][1]);
            const f32x2 gf = hi8 ? mk(s21, s31) : mk(acc[s][1][0], acc[s][1][1]);
            const f32x2 gg = hi8 ? mk(s22, s32) : mk(acc[s][2][0], acc[s][2][1]);
            const f32x2 go = hi8 ? mk(s23, s33) : mk(acc[s][3][0], acc[s][3][1]);
            const unsigned pkd = ewPair(gi, gf, gg, go, cst[s]);
            *(unsigned*)&hd[row8 * HPITCH + wave * 32 + s * 16 + quad * 4 + hi8 * 2] = pkd;
        }
    };

    // Encode cell: x+bias via MFMA on the underused matrix pipe; ks-outer/set/gate
    // inner = 8 independent accumulation chains. af shared by both sets (reads
    // don't double). Prefetch next xa under ew+barrier.
    auto cellE = [&](const __bf16* hs, __bf16* hd, uint2 xd, int tn) -> uint2 {
        B8 xf; xf.i = make_int4((int)xd.x, (int)ones2, (int)xd.y, (int)xd.x);
        bf16x8 af[4];
#pragma unroll
        for (int ks = 0; ks < 4; ++ks)
            af[ks] = *(const bf16x8*)&hs[hrow + ks * 32 + quad * 8];
        const floatx4 z = {0.f, 0.f, 0.f, 0.f};
        floatx4 acc[2][4];
        SETPRIO(1);
#pragma unroll
        for (int s = 0; s < 2; ++s)
#pragma unroll
            for (int g = 0; g < 4; ++g)
                acc[s][g] = __builtin_amdgcn_mfma_f32_16x16x32_bf16(bfx[s][g].v, xf.v, z, 0, 0, 0);
#pragma unroll
        for (int ks = 0; ks < 4; ++ks)
#pragma unroll
            for (int s = 0; s < 2; ++s)
#pragma unroll
                for (int g = 0; g < 4; ++g)
                    acc[s][g] = __builtin_amdgcn_mfma_f32_16x16x32_bf16(bfrag[s][g][ks], af[ks], acc[s][g], 0, 0, 0);
        SETPRIO(0);
        const int ts = (tn < TSTEPS) ? tn : 0;
        const uint2 xn = xa[ts * BR + row8];                // prefetch (consumed next cell)
        finish(acc, hd);
        __syncthreads();
        return xn;
    };

    __syncthreads();
    // seed anti-phase: co-located partner (b and b+256 land on the same CU under
    // XCD round-robin) starts ~half a step late; contention dynamics keep drift.
    if (blockIdx.x & 256) { SSLEEP(7); SSLEEP(7); }

    // ================= encode: 512 steps =================
    uint2 xd = xa[row8];                                    // t = 0
    for (int t = 0; t < TSTEPS; t += 2) {
        xd = cellE(h_lds[0], h_lds[1], xd, t + 1);
        xd = cellE(h_lds[1], h_lds[0], xd, t + 2);
    }

    // ========== transition: fold fc into weights =========
    // W_eff = gs*(W_hh + W_ih*fc_w) (A-layout fold); b_eff exact fp32 in C-layout
    // (beff identical across a shuffle pair: depends only on quad*4+r -> shuffle-safe).
    floatx4 beff[2][4];
#pragma unroll
    for (int s = 0; s < 2; ++s) {
        const int ub = wave * 32 + s * 16 + l15;
#pragma unroll
        for (int g = 0; g < 4; ++g) {
            const int cgA = g * HIDDEN + ub;
            const float wi0 = W_ih[cgA * 2 + 0];
            const float wi1 = W_ih[cgA * 2 + 1];
#pragma unroll
            for (int ks = 0; ks < 4; ++ks) {
                const int k0 = ks * 32 + quad * 8;
                bf16x8 bb = bfrag[s][g][ks];
#pragma unroll
                for (int j = 0; j < 8; ++j)
                    bb[j] = (__bf16)((float)bb[j] + gs[g] * (wi0 * fcw_lds[0][k0 + j]
                                                           + wi1 * fcw_lds[1][k0 + j]));
                bfrag[s][g][ks] = bb;
            }
            floatx4 v;
#pragma unroll
            for (int r = 0; r < 4; ++r) {
                const int cg = g * HIDDEN + wave * 32 + s * 16 + quad * 4 + r;  // C-layout col
                v[r] = gs[g] * (b_ih[cg] + b_hh[cg]
                              + W_ih[cg * 2 + 0] * fcb0 + W_ih[cg * 2 + 1] * fcb1);
            }
            beff[s][g] = v;
        }
    }

    auto cellF = [&](const __bf16* hs, __bf16* hd) {
        bf16x8 af[4];
#pragma unroll
        for (int ks = 0; ks < 4; ++ks)
            af[ks] = *(const bf16x8*)&hs[hrow + ks * 32 + quad * 8];
        floatx4 acc[2][4];
#pragma unroll
        for (int s = 0; s < 2; ++s)
#pragma unroll
            for (int g = 0; g < 4; ++g) acc[s][g] = beff[s][g];  // exact fp32 scaled bias
        SETPRIO(1);
#pragma unroll
        for (int ks = 0; ks < 4; ++ks)
#pragma unroll
            for (int s = 0; s < 2; ++s)
#pragma unroll
                for (int g = 0; g < 4; ++g)
                    acc[s][g] = __builtin_amdgcn_mfma_f32_16x16x32_bf16(bfrag[s][g][ks], af[ks], acc[s][g], 0, 0, 0);
        SETPRIO(0);
        finish(acc, hd);
        __syncthreads();
    };

    // y output only (no feedback): wave0 computes while others run MFMA
    auto emitY = [&](const __bf16* hs, int f) {
        if (wave == 0) {
            const int r = lane & 7, seg = lane >> 3;        // 8 segs x 16 cols
            const __bf16* hp = &hs[r * HPITCH + seg * 16];
            float p0 = 0.f, p1 = 0.f;
#pragma unroll
            for (int js = 0; js < 2; ++js) {
                bf16x8 hv = *(const bf16x8*)&hp[js * 8];
                const float4* f0 = (const float4*)&fcw_lds[0][seg * 16 + js * 8];
                const float4* f1 = (const float4*)&fcw_lds[1][seg * 16 + js * 8];
                float4 a0 = f0[0], b0 = f0[1], a1 = f1[0], b1 = f1[1];
                p0 += (float)hv[0]*a0.x + (float)hv[1]*a0.y + (float)hv[2]*a0.z + (float)hv[3]*a0.w
                    + (float)hv[4]*b0.x + (float)hv[5]*b0.y + (float)hv[6]*b0.z + (float)hv[7]*b0.w;
                p1 += (float)hv[0]*a1.x + (float)hv[1]*a1.y + (float)hv[2]*a1.z + (float)hv[3]*a1.w
                    + (float)hv[4]*b1.x + (float)hv[5]*b1.y + (float)hv[6]*b1.z + (float)hv[7]*b1.w;
            }
            p0 += __shfl_xor(p0, 8); p0 += __shfl_xor(p0, 16); p0 += __shfl_xor(p0, 32);
            p1 += __shfl_xor(p1, 8); p1 += __shfl_xor(p1, 16); p1 += __shfl_xor(p1, 32);
            if (seg == 0) {
                float* op = &out[(size_t)(rb + r) * (2 * NFUT) + f * 2];
                op[0] = p0 + fcb0;
                op[1] = p1 + fcb1;
            }
        }
    };

    // ================= forecast: 50 steps ================
    for (int f = 0; f < NFUT; f += 2) {
        emitY(h_lds[0], f);
        cellF(h_lds[0], h_lds[1]);
        emitY(h_lds[1], f + 1);
        cellF(h_lds[1], h_lds[0]);
    }
}

extern "C" void kernel_launch(void* const* d_in, const int* in_sizes, int n_in,
                              void* d_out, int out_size, void* d_ws, size_t ws_size,
                              hipStream_t stream) {
    const float* x    = (const float*)d_in[0];
    const float* W_ih = (const float*)d_in[1];
    const float* W_hh = (const float*)d_in[2];
    const float* b_ih = (const float*)d_in[3];
    const float* b_hh = (const float*)d_in[4];
    const float* fc_w = (const float*)d_in[5];
    const float* fc_b = (const float*)d_in[6];
    float* out = (float*)d_out;

    const int B = in_sizes[0] / (TSTEPS * 2);   // 4096
    const int grid = B / BR;                    // 512 blocks -> 2 per CU
    lstm_forecast_kernel<<<grid, THREADS, 0, stream>>>(x, W_ih, W_hh, b_ih, b_hh, fc_w, fc_b, out);
}